// Round 1
// baseline (498.350 us; speedup 1.0000x reference)
//
#include <hip/hip_runtime.h>
#include <math.h>

// HybridRBF: out[b] = exp(-sum_d (xn-yn)^2) + (prod_{i<8} cos(x_i-y_i))^2
// xn,yn: per-row normalize with mean, std(ddof=1)+1e-8.
// Quantum part: RY(x)RY(x)RY(-y)RY(-y)|0> -> net angle 2(x-y), a0=cos(x-y).
//
// R3: two changes vs R2 (469 us session-best):
//  1. Drop nontemporal LOADS. nt loads bypass the cached read path; the
//     6.3 TB/s ceiling (m13) is measured with plain cached float4 loads,
//     and our 8-lane/row layout consumes every 64B line fully within one
//     instruction, so nt buys nothing and was costing ~0.57x read BW.
//     (Keep nt on the 4 MB output store - harmless, avoids L2 pollution.)
//  2. Replace the 15 ds_swizzle shuffles (3 dependent lgkmcnt(0) waits)
//     with VALU-pipe DPP butterflies: quad_perm xor1, quad_perm xor2,
//     row_half_mirror to combine quads. Bit-identical sums, zero LDS.
// Layout unchanged: 8 lanes/row, each lane 2x float4 from x and y,
// per-instruction wave access = 8 contiguous 128B segments (lines fully
// used), 5-moment reduction, 1 store per row.

constexpr float EPS = 1e-8f;

typedef float v4f __attribute__((ext_vector_type(4)));

// Butterfly add across the 8-lane row group, entirely on the VALU pipe.
// CTRL: 0xB1 = quad_perm(1,0,3,2) (xor 1), 0x4E = quad_perm(2,3,0,1) (xor 2),
//       0x141 = row_half_mirror (pairs quad {0..3} with {4..7} within each
//       8-lane half-row; after the two quad stages both quads hold their
//       quad-sum, so this is numerically identical to xor 4).
template <int CTRL>
__device__ __forceinline__ float bfly_add(float v) {
    int d = __builtin_amdgcn_update_dpp(0, __builtin_bit_cast(int, v),
                                        CTRL, 0xF, 0xF, true);
    return v + __builtin_bit_cast(float, d);
}

template <int CTRL>
__device__ __forceinline__ float dpp_get(float v) {
    int d = __builtin_amdgcn_update_dpp(0, __builtin_bit_cast(int, v),
                                        CTRL, 0xF, 0xF, true);
    return __builtin_bit_cast(float, d);
}

__global__ __launch_bounds__(256, 8) void hybrid_rbf_kernel(
    const float* __restrict__ x, const float* __restrict__ y,
    float* __restrict__ out, int n_rows) {
    const int tid  = blockIdx.x * blockDim.x + threadIdx.x;
    const int sub  = tid & 7;         // lane within 8-lane row group
    const int row  = tid >> 3;
    if (row >= n_rows) return;

    const v4f* xr = (const v4f*)(x + (size_t)row * 64);
    const v4f* yr = (const v4f*)(y + (size_t)row * 64);
    // first half: floats [4*sub, 4*sub+4); second half: [32+4*sub, ...)
    const v4f xa = xr[sub];
    const v4f xb = xr[sub + 8];
    const v4f ya = yr[sub];
    const v4f yb = yr[sub + 8];

    // per-lane partial raw moments over 8 elements
    float sx  = ((xa.x + xa.y) + (xa.z + xa.w)) + ((xb.x + xb.y) + (xb.z + xb.w));
    float sy  = ((ya.x + ya.y) + (ya.z + ya.w)) + ((yb.x + yb.y) + (yb.z + yb.w));
    float sxx = xa.x*xa.x + xa.y*xa.y + xa.z*xa.z + xa.w*xa.w
              + xb.x*xb.x + xb.y*xb.y + xb.z*xb.z + xb.w*xb.w;
    float syy = ya.x*ya.x + ya.y*ya.y + ya.z*ya.z + ya.w*ya.w
              + yb.x*yb.x + yb.y*yb.y + yb.z*yb.z + yb.w*yb.w;
    float sxy = xa.x*ya.x + xa.y*ya.y + xa.z*ya.z + xa.w*ya.w
              + xb.x*yb.x + xb.y*yb.y + xb.z*yb.z + xb.w*yb.w;

    // DPP butterfly across the 8-lane group (no LDS, no lgkmcnt waits)
    sx  = bfly_add<0xB1>(sx);   sy  = bfly_add<0xB1>(sy);
    sxx = bfly_add<0xB1>(sxx);  syy = bfly_add<0xB1>(syy);
    sxy = bfly_add<0xB1>(sxy);

    sx  = bfly_add<0x4E>(sx);   sy  = bfly_add<0x4E>(sy);
    sxx = bfly_add<0x4E>(sxx);  syy = bfly_add<0x4E>(syy);
    sxy = bfly_add<0x4E>(sxy);

    sx  = bfly_add<0x141>(sx);  sy  = bfly_add<0x141>(sy);
    sxx = bfly_add<0x141>(sxx); syy = bfly_add<0x141>(syy);
    sxy = bfly_add<0x141>(sxy);

    const float inv64 = 1.0f / 64.0f;
    const float mx = sx * inv64;
    const float my = sy * inv64;
    float vx  = sxx - sx * mx;   // sum (x-mx)^2
    float vy  = syy - sy * my;   // sum (y-my)^2
    float cxy = sxy - sx * my;   // sum (x-mx)(y-my)
    vx = fmaxf(vx, 0.0f);
    vy = fmaxf(vy, 0.0f);
    const float stdx = sqrtf(vx * (1.0f / 63.0f)) + EPS;
    const float stdy = sqrtf(vy * (1.0f / 63.0f)) + EPS;
    const float ssq = vx / (stdx * stdx) + vy / (stdy * stdy)
                    - 2.0f * cxy / (stdx * stdy);
    const float classic = __expf(-ssq);   // GAMMA = 1

    // quantum: cols 0..7 live in xa/ya of sub=0 (cols 0..3) and sub=1 (4..7).
    // Compute cos products on ALL lanes (branchless; lanes sub>=2 produce
    // unused values), then one DPP xor1 pairs sub0 with sub1.
    const float p = __cosf(xa.x - ya.x) * __cosf(xa.y - ya.y)
                  * __cosf(xa.z - ya.z) * __cosf(xa.w - ya.w);
    const float q = p * dpp_get<0xB1>(p);   // full 8-wire product on sub 0

    if (sub == 0) {
        __builtin_nontemporal_store(classic + q * q, out + row);
    }
}

extern "C" void kernel_launch(void* const* d_in, const int* in_sizes, int n_in,
                              void* d_out, int out_size, void* d_ws, size_t ws_size,
                              hipStream_t stream) {
    const float* x = (const float*)d_in[0];
    const float* y = (const float*)d_in[1];
    float* out = (float*)d_out;
    const int n_rows = in_sizes[0] / 64;          // B = 1048576
    const long long total = (long long)n_rows * 8;
    const int block = 256;
    const int grid = (int)((total + block - 1) / block);
    hipLaunchKernelGGL(hybrid_rbf_kernel, dim3(grid), dim3(block), 0, stream,
                       x, y, out, n_rows);
}

// Round 2
// 469.629 us; speedup vs baseline: 1.0612x; 1.0612x over previous
//
#include <hip/hip_runtime.h>
#include <math.h>

// HybridRBF: out[b] = exp(-sum_d (xn-yn)^2) + (prod_{i<8} cos(x_i-y_i))^2
// xn,yn: per-row normalize with mean, std(ddof=1)+1e-8.
// Quantum part: RY(x)RY(x)RY(-y)RY(-y)|0> -> net angle 2(x-y), a0=cos(x-y).
//
// R4: controlled single-variable round. R3 (plain loads + launch_bounds(256,8)
// + DPP) regressed 472->498. Revert the two prime suspects:
//   - RESTORE __builtin_nontemporal_load (R2 scheme): streaming data has zero
//     intra-launch reuse; nt avoids allocating 512 MB/iter through the caches.
//   - RESTORE __launch_bounds__(256) with no min-waves arg: the (256,8) form
//     capped VGPRs at 64, right at this kernel's live-set boundary.
// KEEP the DPP butterfly (the one low-risk R3 change): 15 VALU-pipe adds
// replace 15 ds_swizzle + 3 dependent lgkmcnt(0) waits. VALU is ~5% busy.
// Layout unchanged: 8 lanes/row, each lane 2x float4 from x and y,
// 5-moment reduction, 1 store per row.

constexpr float EPS = 1e-8f;

typedef float v4f __attribute__((ext_vector_type(4)));

// Butterfly add across the 8-lane row group, entirely on the VALU pipe.
// CTRL: 0xB1 = quad_perm(1,0,3,2) (xor 1), 0x4E = quad_perm(2,3,0,1) (xor 2),
//       0x141 = row_half_mirror (pairs quad {0..3} with {4..7}; after the two
//       quad stages both quads hold their quad-sum, so this equals xor 4).
template <int CTRL>
__device__ __forceinline__ float bfly_add(float v) {
    int d = __builtin_amdgcn_update_dpp(0, __builtin_bit_cast(int, v),
                                        CTRL, 0xF, 0xF, true);
    return v + __builtin_bit_cast(float, d);
}

template <int CTRL>
__device__ __forceinline__ float dpp_get(float v) {
    int d = __builtin_amdgcn_update_dpp(0, __builtin_bit_cast(int, v),
                                        CTRL, 0xF, 0xF, true);
    return __builtin_bit_cast(float, d);
}

__global__ __launch_bounds__(256) void hybrid_rbf_kernel(
    const float* __restrict__ x, const float* __restrict__ y,
    float* __restrict__ out, int n_rows) {
    const int tid  = blockIdx.x * blockDim.x + threadIdx.x;
    const int sub  = tid & 7;         // lane within 8-lane row group
    const int row  = tid >> 3;
    if (row >= n_rows) return;

    const v4f* xr = (const v4f*)(x + (size_t)row * 64);
    const v4f* yr = (const v4f*)(y + (size_t)row * 64);
    // first half: floats [4*sub, 4*sub+4); second half: [32+4*sub, ...)
    const v4f xa = __builtin_nontemporal_load(xr + sub);
    const v4f xb = __builtin_nontemporal_load(xr + sub + 8);
    const v4f ya = __builtin_nontemporal_load(yr + sub);
    const v4f yb = __builtin_nontemporal_load(yr + sub + 8);

    // per-lane partial raw moments over 8 elements
    float sx  = ((xa.x + xa.y) + (xa.z + xa.w)) + ((xb.x + xb.y) + (xb.z + xb.w));
    float sy  = ((ya.x + ya.y) + (ya.z + ya.w)) + ((yb.x + yb.y) + (yb.z + yb.w));
    float sxx = xa.x*xa.x + xa.y*xa.y + xa.z*xa.z + xa.w*xa.w
              + xb.x*xb.x + xb.y*xb.y + xb.z*xb.z + xb.w*xb.w;
    float syy = ya.x*ya.x + ya.y*ya.y + ya.z*ya.z + ya.w*ya.w
              + yb.x*yb.x + yb.y*yb.y + yb.z*yb.z + yb.w*yb.w;
    float sxy = xa.x*ya.x + xa.y*ya.y + xa.z*ya.z + xa.w*ya.w
              + xb.x*yb.x + xb.y*yb.y + xb.z*yb.z + xb.w*yb.w;

    // DPP butterfly across the 8-lane group (no LDS, no lgkmcnt waits)
    sx  = bfly_add<0xB1>(sx);   sy  = bfly_add<0xB1>(sy);
    sxx = bfly_add<0xB1>(sxx);  syy = bfly_add<0xB1>(syy);
    sxy = bfly_add<0xB1>(sxy);

    sx  = bfly_add<0x4E>(sx);   sy  = bfly_add<0x4E>(sy);
    sxx = bfly_add<0x4E>(sxx);  syy = bfly_add<0x4E>(syy);
    sxy = bfly_add<0x4E>(sxy);

    sx  = bfly_add<0x141>(sx);  sy  = bfly_add<0x141>(sy);
    sxx = bfly_add<0x141>(sxx); syy = bfly_add<0x141>(syy);
    sxy = bfly_add<0x141>(sxy);

    const float inv64 = 1.0f / 64.0f;
    const float mx = sx * inv64;
    const float my = sy * inv64;
    float vx  = sxx - sx * mx;   // sum (x-mx)^2
    float vy  = syy - sy * my;   // sum (y-my)^2
    float cxy = sxy - sx * my;   // sum (x-mx)(y-my)
    vx = fmaxf(vx, 0.0f);
    vy = fmaxf(vy, 0.0f);
    const float stdx = sqrtf(vx * (1.0f / 63.0f)) + EPS;
    const float stdy = sqrtf(vy * (1.0f / 63.0f)) + EPS;
    const float ssq = vx / (stdx * stdx) + vy / (stdy * stdy)
                    - 2.0f * cxy / (stdx * stdy);
    const float classic = __expf(-ssq);   // GAMMA = 1

    // quantum: cols 0..7 live in xa/ya of sub=0 (cols 0..3) and sub=1 (4..7).
    // Branchless cos products on all lanes, then one DPP xor1 pairs sub0/sub1.
    const float p = __cosf(xa.x - ya.x) * __cosf(xa.y - ya.y)
                  * __cosf(xa.z - ya.z) * __cosf(xa.w - ya.w);
    const float q = p * dpp_get<0xB1>(p);   // full 8-wire product on sub 0

    if (sub == 0) {
        __builtin_nontemporal_store(classic + q * q, out + row);
    }
}

extern "C" void kernel_launch(void* const* d_in, const int* in_sizes, int n_in,
                              void* d_out, int out_size, void* d_ws, size_t ws_size,
                              hipStream_t stream) {
    const float* x = (const float*)d_in[0];
    const float* y = (const float*)d_in[1];
    float* out = (float*)d_out;
    const int n_rows = in_sizes[0] / 64;          // B = 1048576
    const long long total = (long long)n_rows * 8;
    const int block = 256;
    const int grid = (int)((total + block - 1) / block);
    hipLaunchKernelGGL(hybrid_rbf_kernel, dim3(grid), dim3(block), 0, stream,
                       x, y, out, n_rows);
}